// Round 3
// baseline (694.662 us; speedup 1.0000x reference)
//
#include <hip/hip_runtime.h>
#include <hip/hip_bf16.h>

// VQ EuclideanCodebook, round 3: bf16-MFMA candidate filter + exact f32 re-rank.
//
// Phase A (MFMA, no LDS): approx scores s = e2 - 2*(x_bf.e_bf) via
// mfma_f32_32x32x16_bf16. Sweep1: per-row min. Sweep2: collect codes with
// s <= min + margin, margin rigorously >= 2*max approx error. Candidates
// appended to per-row lists (CAP=48, overflow -> exact full-scan fallback).
// Phase B: exact f32 re-rank of candidates with the round-2 pipeline
// (ascending-d fmaf, dist=(x2-2dot)+e2), then gather/scatter epilogue.

#define NROWS 262144
#define KCODES 1024
#define DDIM 64
#define CAP 48

typedef __attribute__((ext_vector_type(8)))  short short8;
typedef __attribute__((ext_vector_type(16))) float f32x16;

__device__ __forceinline__ unsigned short f2bf(float f) {
    unsigned u = __float_as_uint(f);
    unsigned r = u + 0x7fffu + ((u >> 16) & 1u);   // RNE to bf16
    return (unsigned short)(r >> 16);
}

// ---- prep: e2 (exact f32, ascending fmaf), E->bf16, max ||e||^2 ----
__global__ __launch_bounds__(256) void vq_prep(
    const float* __restrict__ embed, unsigned short* __restrict__ eb,
    float* __restrict__ e2f, float* __restrict__ enmax2)
{
    const int k = blockIdx.x * 256 + threadIdx.x;   // 0..1023
    const float* er = embed + (size_t)k * DDIM;
    float s = 0.f;
    #pragma unroll
    for (int d = 0; d < DDIM; ++d) { float v = er[d]; s = fmaf(v, v, s); }
    e2f[k] = s;
    #pragma unroll
    for (int d = 0; d < DDIM; ++d) eb[(size_t)k * DDIM + d] = f2bf(er[d]);
    atomicMax((int*)enmax2, __float_as_int(s));     // s >= 0: int-monotone
}

// ---- phase A: MFMA approx sweep, candidate collection ----
__global__ __launch_bounds__(256, 2) void vq_mfma(
    const float* __restrict__ x, const unsigned short* __restrict__ eb,
    const float* __restrict__ e2f, const float* __restrict__ enmax2,
    int* __restrict__ cnt, int* __restrict__ candq)
{
    const int t    = threadIdx.x;
    const int lane = t & 63;
    const int wid  = t >> 6;
    const int lo   = lane & 31;
    const int hi   = lane >> 5;
    const int row0 = blockIdx.x * 256 + wid * 64;   // this wave: rows row0..row0+63

    // ---- A fragments: 2 tiles x 32 rows, fully register-resident ----
    // layout assumption: A row = lane&31, k = 16*i + 8*(lane>>5) + j
    short8 af[2][4];
    float  xsq[2];
    #pragma unroll
    for (int tt = 0; tt < 2; ++tt) {
        const float* xr = x + (size_t)(row0 + tt * 32 + lo) * DDIM;
        float s = 0.f;
        #pragma unroll
        for (int i = 0; i < 4; ++i) {
            const float4 a = *reinterpret_cast<const float4*>(xr + 16 * i + 8 * hi);
            const float4 b = *reinterpret_cast<const float4*>(xr + 16 * i + 8 * hi + 4);
            short8 f;
            f[0] = (short)f2bf(a.x); f[1] = (short)f2bf(a.y);
            f[2] = (short)f2bf(a.z); f[3] = (short)f2bf(a.w);
            f[4] = (short)f2bf(b.x); f[5] = (short)f2bf(b.y);
            f[6] = (short)f2bf(b.z); f[7] = (short)f2bf(b.w);
            af[tt][i] = f;
            s = fmaf(a.x, a.x, s); s = fmaf(a.y, a.y, s);
            s = fmaf(a.z, a.z, s); s = fmaf(a.w, a.w, s);
            s = fmaf(b.x, b.x, s); s = fmaf(b.y, b.y, s);
            s = fmaf(b.z, b.z, s); s = fmaf(b.w, b.w, s);
        }
        xsq[tt] = s;
    }
    // full ||x||^2 per row (halves hold complementary d-windows), then tile max
    const float en2 = *enmax2;
    float margin[2];
    #pragma unroll
    for (int tt = 0; tt < 2; ++tt) {
        float v = xsq[tt] + __shfl_xor(xsq[tt], 32);
        v = fmaxf(v, __shfl_xor(v, 1));  v = fmaxf(v, __shfl_xor(v, 2));
        v = fmaxf(v, __shfl_xor(v, 4));  v = fmaxf(v, __shfl_xor(v, 8));
        v = fmaxf(v, __shfl_xor(v, 16));
        margin[tt] = 0.015625f * sqrtf(v * en2) + 1e-3f;   // 2^-6 * ||x|| * ||e||max
    }

    f32x16 best0, best1;
    #pragma unroll
    for (int r = 0; r < 16; ++r) { best0[r] = 3.4e38f; best1[r] = 3.4e38f; }

    // ---- sweep 1: per-(lane,reg) running min ----
    for (int ch = 0; ch < 32; ++ch) {
        const int c0 = ch * 32;
        short8 bfr[4];
        #pragma unroll
        for (int i = 0; i < 4; ++i)
            bfr[i] = *reinterpret_cast<const short8*>(
                eb + (size_t)(c0 + lo) * DDIM + 16 * i + 8 * hi);
        const float e2l = e2f[c0 + lo];
        f32x16 a0, a1;
        #pragma unroll
        for (int r = 0; r < 16; ++r) { a0[r] = 0.f; a1[r] = 0.f; }
        #pragma unroll
        for (int i = 0; i < 4; ++i) {
            a0 = __builtin_amdgcn_mfma_f32_32x32x16_bf16(af[0][i], bfr[i], a0, 0, 0, 0);
            a1 = __builtin_amdgcn_mfma_f32_32x32x16_bf16(af[1][i], bfr[i], a1, 0, 0, 0);
        }
        #pragma unroll
        for (int r = 0; r < 16; ++r) {
            best0[r] = fminf(best0[r], fmaf(-2.f, a0[r], e2l));
            best1[r] = fminf(best1[r], fmaf(-2.f, a1[r], e2l));
        }
    }

    // ---- per-row min across the 32 lanes of each half, + margin -> threshold ----
    #pragma unroll
    for (int r = 0; r < 16; ++r) {
        float v0 = best0[r], v1 = best1[r];
        v0 = fminf(v0, __shfl_xor(v0, 1));  v1 = fminf(v1, __shfl_xor(v1, 1));
        v0 = fminf(v0, __shfl_xor(v0, 2));  v1 = fminf(v1, __shfl_xor(v1, 2));
        v0 = fminf(v0, __shfl_xor(v0, 4));  v1 = fminf(v1, __shfl_xor(v1, 4));
        v0 = fminf(v0, __shfl_xor(v0, 8));  v1 = fminf(v1, __shfl_xor(v1, 8));
        v0 = fminf(v0, __shfl_xor(v0, 16)); v1 = fminf(v1, __shfl_xor(v1, 16));
        best0[r] = v0 + margin[0];          // best* now holds thresholds T
        best1[r] = v1 + margin[1];
    }

    // ---- sweep 2: recompute, collect candidates within threshold ----
    for (int ch = 0; ch < 32; ++ch) {
        const int c0 = ch * 32;
        short8 bfr[4];
        #pragma unroll
        for (int i = 0; i < 4; ++i)
            bfr[i] = *reinterpret_cast<const short8*>(
                eb + (size_t)(c0 + lo) * DDIM + 16 * i + 8 * hi);
        const float e2l = e2f[c0 + lo];
        f32x16 a0, a1;
        #pragma unroll
        for (int r = 0; r < 16; ++r) { a0[r] = 0.f; a1[r] = 0.f; }
        #pragma unroll
        for (int i = 0; i < 4; ++i) {
            a0 = __builtin_amdgcn_mfma_f32_32x32x16_bf16(af[0][i], bfr[i], a0, 0, 0, 0);
            a1 = __builtin_amdgcn_mfma_f32_32x32x16_bf16(af[1][i], bfr[i], a1, 0, 0, 0);
        }
        #pragma unroll
        for (int r = 0; r < 16; ++r) {
            const int rr = (r & 3) + 8 * (r >> 2) + 4 * hi;   // C/D row (verified map)
            const float d0 = fmaf(-2.f, a0[r], e2l);
            if (d0 <= best0[r]) {
                const int row = row0 + rr;
                const int idx = atomicAdd(cnt + row, 1);
                if (idx < CAP) candq[(size_t)row * 64 + idx] = c0 + lo;
            }
            const float d1 = fmaf(-2.f, a1[r], e2l);
            if (d1 <= best1[r]) {
                const int row = row0 + 32 + rr;
                const int idx = atomicAdd(cnt + row, 1);
                if (idx < CAP) candq[(size_t)row * 64 + idx] = c0 + lo;
            }
        }
    }
}

// ---- phase B: exact f32 re-rank + gather/scatter epilogue ----
#define LDR 65
__global__ __launch_bounds__(256) void vq_rerank(
    const float* __restrict__ x, const float* __restrict__ embed,
    const float* __restrict__ e2f, const int* __restrict__ cnt,
    float* __restrict__ out_q, float* __restrict__ out_ind,
    float* __restrict__ bins, float* __restrict__ embed_sum)
{
    __shared__ float xs[256 * LDR];
    __shared__ int   inds[256];
    const int t    = threadIdx.x;
    const int row0 = blockIdx.x * 256;
    int* candq = (int*)out_q;

    // stage x tile [row][d], stride 65 (conflict-free scalar reads)
    #pragma unroll
    for (int i = 0; i < 16; ++i) {
        int f = t + i * 256;               // 0..4095 float4s
        int r = f >> 4, dq = f & 15;
        const float4 v = *reinterpret_cast<const float4*>(
            x + (size_t)(row0 + r) * DDIM + dq * 4);
        xs[r * LDR + dq * 4 + 0] = v.x; xs[r * LDR + dq * 4 + 1] = v.y;
        xs[r * LDR + dq * 4 + 2] = v.z; xs[r * LDR + dq * 4 + 3] = v.w;
    }
    __syncthreads();

    const int row = row0 + t;
    const int c   = cnt[row];
    int bi;
    if (c == 1) {
        bi = candq[(size_t)row * 64];
    } else {
        float x2 = 0.f;
        for (int d = 0; d < DDIM; ++d) { float v = xs[t * LDR + d]; x2 = fmaf(v, v, x2); }
        float bv = 3.4e38f; bi = 0x7fffffff;
        if (c <= CAP) {
            for (int ci = 0; ci < c; ++ci) {
                const int k = candq[(size_t)row * 64 + ci];
                const float* er = embed + (size_t)k * DDIM;
                float dot = 0.f;
                for (int d = 0; d < DDIM; ++d) dot = fmaf(xs[t * LDR + d], er[d], dot);
                const float dist = (x2 - 2.0f * dot) + e2f[k];
                if (dist < bv || (dist == bv && k < bi)) { bv = dist; bi = k; }
            }
        } else {   // overflow fallback: exact full scan (ascending k keeps first on ties)
            for (int k = 0; k < KCODES; ++k) {
                const float* er = embed + (size_t)k * DDIM;
                float dot = 0.f;
                for (int d = 0; d < DDIM; ++d) dot = fmaf(xs[t * LDR + d], er[d], dot);
                const float dist = (x2 - 2.0f * dot) + e2f[k];
                if (dist < bv) { bv = dist; bi = k; }
            }
        }
    }
    inds[t] = bi;
    out_ind[row] = (float)bi;
    unsafeAtomicAdd(bins + bi, 1.0f);
    __syncthreads();

    // gather quantize + scatter embed_sum
    #pragma unroll
    for (int i = 0; i < 16; ++i) {
        int f = t + i * 256;
        int r = f >> 4, dq = f & 15;
        int code = inds[r];
        const float4 ev = *reinterpret_cast<const float4*>(
            embed + (size_t)code * DDIM + dq * 4);
        *reinterpret_cast<float4*>(out_q + (size_t)(row0 + r) * DDIM + dq * 4) = ev;
        unsafeAtomicAdd(embed_sum + code * DDIM + dq * 4 + 0, xs[r * LDR + dq * 4 + 0]);
        unsafeAtomicAdd(embed_sum + code * DDIM + dq * 4 + 1, xs[r * LDR + dq * 4 + 1]);
        unsafeAtomicAdd(embed_sum + code * DDIM + dq * 4 + 2, xs[r * LDR + dq * 4 + 2]);
        unsafeAtomicAdd(embed_sum + code * DDIM + dq * 4 + 3, xs[r * LDR + dq * 4 + 3]);
    }
}

// ---- finalize: EMA + Laplace smoothing (unchanged from round 2) ----
__global__ __launch_bounds__(1024) void vq_finalize(
    const float* __restrict__ cluster_size, const float* __restrict__ embed_avg,
    float* __restrict__ out_cs, float* __restrict__ out_eavg,
    float* __restrict__ out_enorm)
{
    __shared__ float red[KCODES];
    __shared__ float css[KCODES];
    const int t = threadIdx.x;

    const float csn = cluster_size[t] * 0.1f + out_cs[t] * 0.9f;
    red[t] = csn;
    __syncthreads();
    for (int s = 512; s > 0; s >>= 1) {
        if (t < s) red[t] += red[t + s];
        __syncthreads();
    }
    const float n = red[0];
    out_cs[t] = csn;
    css[t] = (csn + 1e-5f) / (n + (float)(KCODES * 1e-5)) * n;
    __syncthreads();

    #pragma unroll
    for (int i = 0; i < 16; ++i) {
        int f4 = t + i * 1024;
        int k  = f4 >> 4;
        const float4 ea = reinterpret_cast<const float4*>(embed_avg)[f4];
        const float4 su = reinterpret_cast<const float4*>(out_eavg)[f4];
        const float  cc = css[k];
        float4 ean, en;
        ean.x = ea.x * 0.1f + su.x * 0.9f; en.x = ean.x / cc;
        ean.y = ea.y * 0.1f + su.y * 0.9f; en.y = ean.y / cc;
        ean.z = ea.z * 0.1f + su.z * 0.9f; en.z = ean.z / cc;
        ean.w = ea.w * 0.1f + su.w * 0.9f; en.w = ean.w / cc;
        reinterpret_cast<float4*>(out_eavg)[f4]  = ean;
        reinterpret_cast<float4*>(out_enorm)[f4] = en;
    }
}

extern "C" void kernel_launch(void* const* d_in, const int* in_sizes, int n_in,
                              void* d_out, int out_size, void* d_ws, size_t ws_size,
                              hipStream_t stream)
{
    const float* x            = (const float*)d_in[0];
    const float* embed        = (const float*)d_in[1];
    const float* cluster_size = (const float*)d_in[2];
    const float* embed_avg    = (const float*)d_in[3];

    float* out      = (float*)d_out;
    float* out_q    = out;                                   // N*D (phase-A cand slots, then quantize)
    float* out_ind  = out_q + (size_t)NROWS * DDIM;          // N   (phase-A counters, then indices)
    float* out_cs   = out_ind + NROWS;                       // K   (bins accumulator)
    float* out_eavg = out_cs + KCODES;                       // K*D (embed_sum accumulator)
    float* out_en   = out_eavg + (size_t)KCODES * DDIM;      // K*D (prep scratch, then enorm)

    unsigned short* eb = (unsigned short*)out_en;            // K*D bf16 = 128 KB
    float* e2f    = out_en + 32768;                          // K floats
    float* enmax2 = out_en + 32768 + KCODES;                 // 1 float

    // zero counters + bins + embed_sum (contiguous), and enmax2
    hipMemsetAsync(out_ind, 0, (size_t)(NROWS + KCODES + KCODES * DDIM) * 4, stream);
    hipMemsetAsync(enmax2, 0, 4, stream);

    vq_prep<<<KCODES / 256, 256, 0, stream>>>(embed, eb, e2f, enmax2);
    vq_mfma<<<NROWS / 256, 256, 0, stream>>>(x, eb, e2f, enmax2,
                                             (int*)out_ind, (int*)out_q);
    vq_rerank<<<NROWS / 256, 256, 0, stream>>>(x, embed, e2f, (int*)out_ind,
                                               out_q, out_ind, out_cs, out_eavg);
    vq_finalize<<<1, 1024, 0, stream>>>(cluster_size, embed_avg, out_cs, out_eavg, out_en);
}

// Round 4
// 536.174 us; speedup vs baseline: 1.2956x; 1.2956x over previous
//
#include <hip/hip_runtime.h>
#include <hip/hip_bf16.h>

// VQ EuclideanCodebook round 4: MFMA candidate filter (LDS-staged E, per-row
// rigorous margin) + wave re-rank of multi-candidate rows + atomic-free
// count-sort embed_sum/bins pipeline.

#define NROWS 262144
#define KCODES 1024
#define DDIM 64
#define CAPL 8

typedef __attribute__((ext_vector_type(8)))  short short8;
typedef __attribute__((ext_vector_type(16))) float f32x16;

__device__ __forceinline__ unsigned short f2bf(float f) {
    unsigned u = __float_as_uint(f);
    unsigned r = u + 0x7fffu + ((u >> 16) & 1u);   // RNE to bf16
    return (unsigned short)(r >> 16);
}

// ---- prep: e2 (exact f32, ascending fmaf), E->bf16, max ||e||^2 ----
__global__ __launch_bounds__(256) void vq_prep(
    const float* __restrict__ embed, unsigned short* __restrict__ eb,
    float* __restrict__ e2f, float* __restrict__ enmax2)
{
    const int k = blockIdx.x * 256 + threadIdx.x;   // 0..1023
    const float* er = embed + (size_t)k * DDIM;
    float s = 0.f;
    #pragma unroll
    for (int d = 0; d < DDIM; ++d) { float v = er[d]; s = fmaf(v, v, s); }
    e2f[k] = s;
    #pragma unroll
    for (int d = 0; d < DDIM; ++d) eb[(size_t)k * DDIM + d] = f2bf(er[d]);
    atomicMax((int*)enmax2, __float_as_int(s));     // s >= 0: int-monotone
}

// ---- phase A: MFMA approx sweeps, candidate collection, single-cand finalize ----
__global__ __launch_bounds__(512, 4) void vq_phaseA(
    const float* __restrict__ x, const unsigned short* __restrict__ eb,
    const float* __restrict__ e2f, const float* __restrict__ enmax2,
    float* __restrict__ out_ind, int* __restrict__ candg, int* __restrict__ cntg,
    int* __restrict__ wl, int* __restrict__ gcount)
{
    __shared__ __align__(16) unsigned short ebs[8 * 32 * 64];  // 32 KB, swizzled
    __shared__ float norm2L[256];
    __shared__ int   cntL[256];
    __shared__ int   candL[256][CAPL];
    __shared__ int   mcount, mbase;

    const int t    = threadIdx.x;
    const int lane = t & 63;
    const int wid  = t >> 6;
    const int lo   = lane & 31;
    const int hi   = lane >> 5;
    const int rowb = blockIdx.x * 256;
    const int myrow = rowb + wid * 32 + lo;

    // A fragments (row=lane&31, k=16i+8hi+j) + row norms
    short8 af[4];
    float xsq = 0.f;
    {
        const float* xr = x + (size_t)myrow * DDIM;
        #pragma unroll
        for (int i = 0; i < 4; ++i) {
            const float4 a = *reinterpret_cast<const float4*>(xr + 16 * i + 8 * hi);
            const float4 b = *reinterpret_cast<const float4*>(xr + 16 * i + 8 * hi + 4);
            short8 f;
            f[0] = (short)f2bf(a.x); f[1] = (short)f2bf(a.y);
            f[2] = (short)f2bf(a.z); f[3] = (short)f2bf(a.w);
            f[4] = (short)f2bf(b.x); f[5] = (short)f2bf(b.y);
            f[6] = (short)f2bf(b.z); f[7] = (short)f2bf(b.w);
            af[i] = f;
            xsq = fmaf(a.x, a.x, xsq); xsq = fmaf(a.y, a.y, xsq);
            xsq = fmaf(a.z, a.z, xsq); xsq = fmaf(a.w, a.w, xsq);
            xsq = fmaf(b.x, b.x, xsq); xsq = fmaf(b.y, b.y, xsq);
            xsq = fmaf(b.z, b.z, xsq); xsq = fmaf(b.w, b.w, xsq);
        }
    }
    const float n2full = xsq + __shfl_xor(xsq, 32);
    if (hi == 0) norm2L[wid * 32 + lo] = n2full;
    if (t < 256) cntL[t] = 0;
    if (t == 0) mcount = 0;
    const float en2 = *enmax2;

    f32x16 best;
    #pragma unroll
    for (int r = 0; r < 16; ++r) best[r] = 3.4e38f;

    // ---------- sweep 1 ----------
    for (int p = 0; p < 4; ++p) {
        __syncthreads();
        #pragma unroll
        for (int it = 0; it < 4; ++it) {       // stage 16 KB of eb, swizzled
            const int f16  = t + it * 512;     // 0..2047 16B segments
            const int ch8  = f16 >> 8;
            const int r    = f16 & 255;
            const int code = r >> 3, slot = r & 7;
            const short8 v = *reinterpret_cast<const short8*>(eb + (size_t)p * 16384 + f16 * 8);
            *reinterpret_cast<short8*>((char*)ebs + ch8 * 4096 + code * 128 +
                                       ((slot ^ (code & 7)) << 4)) = v;
        }
        __syncthreads();
        for (int c8 = 0; c8 < 8; ++c8) {
            const int ch = p * 8 + c8;
            short8 bfr[4];
            #pragma unroll
            for (int i = 0; i < 4; ++i) {
                const int slot = 2 * i + hi;
                bfr[i] = *reinterpret_cast<const short8*>(
                    (char*)ebs + c8 * 4096 + lo * 128 + (((slot ^ (lo & 7))) << 4));
            }
            const float e2l = e2f[ch * 32 + lo];
            f32x16 acc;
            #pragma unroll
            for (int r = 0; r < 16; ++r) acc[r] = 0.f;
            #pragma unroll
            for (int i = 0; i < 4; ++i)
                acc = __builtin_amdgcn_mfma_f32_32x32x16_bf16(af[i], bfr[i], acc, 0, 0, 0);
            #pragma unroll
            for (int r = 0; r < 16; ++r)
                best[r] = fminf(best[r], fmaf(-2.f, acc[r], e2l));
        }
    }

    // per-row min reduce (within hi-half) + rigorous per-row margin -> threshold
    #pragma unroll
    for (int r = 0; r < 16; ++r) {
        float v = best[r];
        v = fminf(v, __shfl_xor(v, 1));  v = fminf(v, __shfl_xor(v, 2));
        v = fminf(v, __shfl_xor(v, 4));  v = fminf(v, __shfl_xor(v, 8));
        v = fminf(v, __shfl_xor(v, 16));
        const int rr = (r & 3) + 8 * (r >> 2) + 4 * hi;
        const float nr2 = norm2L[wid * 32 + rr];
        best[r] = v + 0.03125f * sqrtf(nr2 * en2) + 1e-4f;   // 2^-5*||x||*||e||max
    }

    // ---------- sweep 2: recompute, collect candidates ----------
    for (int p = 0; p < 4; ++p) {
        __syncthreads();
        #pragma unroll
        for (int it = 0; it < 4; ++it) {
            const int f16  = t + it * 512;
            const int ch8  = f16 >> 8;
            const int r    = f16 & 255;
            const int code = r >> 3, slot = r & 7;
            const short8 v = *reinterpret_cast<const short8*>(eb + (size_t)p * 16384 + f16 * 8);
            *reinterpret_cast<short8*>((char*)ebs + ch8 * 4096 + code * 128 +
                                       ((slot ^ (code & 7)) << 4)) = v;
        }
        __syncthreads();
        for (int c8 = 0; c8 < 8; ++c8) {
            const int ch = p * 8 + c8;
            short8 bfr[4];
            #pragma unroll
            for (int i = 0; i < 4; ++i) {
                const int slot = 2 * i + hi;
                bfr[i] = *reinterpret_cast<const short8*>(
                    (char*)ebs + c8 * 4096 + lo * 128 + (((slot ^ (lo & 7))) << 4));
            }
            const float e2l = e2f[ch * 32 + lo];
            f32x16 acc;
            #pragma unroll
            for (int r = 0; r < 16; ++r) acc[r] = 0.f;
            #pragma unroll
            for (int i = 0; i < 4; ++i)
                acc = __builtin_amdgcn_mfma_f32_32x32x16_bf16(af[i], bfr[i], acc, 0, 0, 0);
            #pragma unroll
            for (int r = 0; r < 16; ++r) {
                const float d0 = fmaf(-2.f, acc[r], e2l);
                if (d0 <= best[r]) {
                    const int rr = (r & 3) + 8 * (r >> 2) + 4 * hi;
                    const int rl = wid * 32 + rr;
                    const int idx = atomicAdd(&cntL[rl], 1);
                    if (idx < CAPL) candL[rl][idx] = ch * 32 + lo;
                }
            }
        }
    }
    __syncthreads();

    // finalize single-candidate rows; enqueue multi rows
    int my = -1, c = 0;
    if (t < 256) {
        c = cntL[t];
        if (c == 1) out_ind[rowb + t] = (float)candL[t][0];
        else        my = atomicAdd(&mcount, 1);
    }
    __syncthreads();
    if (t == 0) mbase = atomicAdd(gcount, mcount);
    __syncthreads();
    if (my >= 0) {
        const int row = rowb + t;
        wl[mbase + my] = row;
        cntg[row] = c;
        const int cw = c < CAPL ? c : CAPL;
        for (int j = 0; j < cw; ++j) candg[row * 8 + j] = candL[t][j];
    }
}

// ---- wave re-rank of multi-candidate rows (exact f32, reference op order) ----
__global__ __launch_bounds__(256) void vq_rerank(
    const float* __restrict__ x, const float* __restrict__ embed,
    const float* __restrict__ e2f, const int* __restrict__ wl,
    const int* __restrict__ gcount, const int* __restrict__ cntg,
    const int* __restrict__ candg, float* __restrict__ out_ind)
{
    const int t    = threadIdx.x;
    const int lane = t & 63;
    const int gw   = (blockIdx.x * 256 + t) >> 6;
    const int nw   = (gridDim.x * 256) >> 6;
    const int n    = *gcount;

    for (int e = gw; e < n; e += nw) {
        const int row = wl[e];
        float xv[DDIM];
        {
            const float4* xp = reinterpret_cast<const float4*>(x + (size_t)row * DDIM);
            #pragma unroll
            for (int q = 0; q < 16; ++q) {
                const float4 v = xp[q];
                xv[q*4+0] = v.x; xv[q*4+1] = v.y; xv[q*4+2] = v.z; xv[q*4+3] = v.w;
            }
        }
        float x2 = 0.f;
        #pragma unroll
        for (int d = 0; d < DDIM; ++d) x2 = fmaf(xv[d], xv[d], x2);

        const int c = cntg[row];
        float bv; int bk;
        if (c <= CAPL) {
            if (lane < c) {
                const int k = candg[row * 8 + lane];
                const float* er = embed + (size_t)k * DDIM;
                float dot = 0.f;
                #pragma unroll
                for (int d = 0; d < DDIM; ++d) dot = fmaf(xv[d], er[d], dot);
                bv = (x2 - 2.0f * dot) + e2f[k];
                bk = k;
            } else { bv = 3.4e38f; bk = 0x7fffffff; }
        } else {   // overflow: exact full scan, lane-strided, ascending k per lane
            bv = 3.4e38f; bk = 0x7fffffff;
            for (int k = lane; k < KCODES; k += 64) {
                const float* er = embed + (size_t)k * DDIM;
                float dot = 0.f;
                #pragma unroll
                for (int d = 0; d < DDIM; ++d) dot = fmaf(xv[d], er[d], dot);
                const float dist = (x2 - 2.0f * dot) + e2f[k];
                if (dist < bv) { bv = dist; bk = k; }
            }
        }
        // lexicographic (value, index) min over 64 lanes == first-min argmin
        #pragma unroll
        for (int s = 1; s < 64; s <<= 1) {
            const float ov = __shfl_xor(bv, s);
            const int   ok = __shfl_xor(bk, s);
            if (ov < bv || (ov == bv && ok < bk)) { bv = ov; bk = ok; }
        }
        if (lane == 0) out_ind[row] = (float)bk;
    }
}

// ---- histogram (int, LDS-aggregated) ----
__global__ __launch_bounds__(256) void vq_hist(
    const float* __restrict__ out_ind, int* __restrict__ bins_i)
{
    __shared__ int h[KCODES];
    const int t = threadIdx.x;
    #pragma unroll
    for (int j = 0; j < 4; ++j) h[t + 256 * j] = 0;
    __syncthreads();
    const int row = blockIdx.x * 256 + t;
    atomicAdd(&h[(int)out_ind[row]], 1);
    __syncthreads();
    #pragma unroll
    for (int j = 0; j < 4; ++j) {
        const int v = h[t + 256 * j];
        if (v) atomicAdd(bins_i + t + 256 * j, v);
    }
}

// ---- exclusive prefix over bins -> offs, cursor ----
__global__ __launch_bounds__(1024) void vq_prefix(
    const int* __restrict__ bins_i, int* __restrict__ offs, int* __restrict__ cursor)
{
    __shared__ int s[KCODES];
    const int t = threadIdx.x;
    const int b = bins_i[t];
    s[t] = b;
    __syncthreads();
    for (int d = 1; d < KCODES; d <<= 1) {
        const int v = (t >= d) ? s[t - d] : 0;
        __syncthreads();
        s[t] += v;
        __syncthreads();
    }
    const int excl = s[t] - b;
    offs[t] = excl;
    cursor[t] = excl;
}

// ---- scatter row ids into code-sorted order ----
__global__ __launch_bounds__(256) void vq_scatter(
    const float* __restrict__ out_ind, int* __restrict__ cursor, int* __restrict__ sorted)
{
    const int row  = blockIdx.x * 256 + threadIdx.x;
    const int code = (int)out_ind[row];
    const int pos  = atomicAdd(cursor + code, 1);
    sorted[pos] = row;
}

// ---- per-code gather-reduce: embed_sum (no atomics) ----
__global__ __launch_bounds__(256) void vq_reduce(
    const float* __restrict__ x, const int* __restrict__ sorted,
    const int* __restrict__ offs, const int* __restrict__ bins_i,
    float* __restrict__ esum)
{
    __shared__ float part[4][DDIM];
    const int t = threadIdx.x, lane = t & 63, w = t >> 6;
    const int k = blockIdx.x;
    const int off = offs[k], n = bins_i[k];
    float a0 = 0.f, a1 = 0.f;
    for (int i = w; i < n; i += 8) {
        const int r0 = sorted[off + i];
        const float v0 = x[(size_t)r0 * DDIM + lane];
        float v1 = 0.f;
        if (i + 4 < n) { const int r1 = sorted[off + i + 4]; v1 = x[(size_t)r1 * DDIM + lane]; }
        a0 += v0; a1 += v1;
    }
    part[w][lane] = a0 + a1;
    __syncthreads();
    if (t < DDIM)
        esum[(size_t)k * DDIM + t] = ((part[0][t] + part[1][t]) + part[2][t]) + part[3][t];
}

// ---- finalize: EMA + Laplace smoothing ----
__global__ __launch_bounds__(1024) void vq_finalize(
    const float* __restrict__ cluster_size, const float* __restrict__ embed_avg,
    const int* __restrict__ bins_i, float* __restrict__ out_cs,
    float* __restrict__ out_eavg, float* __restrict__ out_enorm)
{
    __shared__ float red[KCODES];
    __shared__ float css[KCODES];
    const int t = threadIdx.x;

    const float csn = cluster_size[t] * 0.1f + (float)bins_i[t] * 0.9f;
    red[t] = csn;
    __syncthreads();
    for (int s = 512; s > 0; s >>= 1) {
        if (t < s) red[t] += red[t + s];
        __syncthreads();
    }
    const float n = red[0];
    out_cs[t] = csn;
    css[t] = (csn + 1e-5f) / (n + (float)(KCODES * 1e-5)) * n;
    __syncthreads();

    #pragma unroll
    for (int i = 0; i < 16; ++i) {
        const int f4 = t + i * 1024;
        const int k  = f4 >> 4;
        const float4 ea = reinterpret_cast<const float4*>(embed_avg)[f4];
        const float4 su = reinterpret_cast<const float4*>(out_eavg)[f4];
        const float  cc = css[k];
        float4 ean, en;
        ean.x = ea.x * 0.1f + su.x * 0.9f; en.x = ean.x / cc;
        ean.y = ea.y * 0.1f + su.y * 0.9f; en.y = ean.y / cc;
        ean.z = ea.z * 0.1f + su.z * 0.9f; en.z = ean.z / cc;
        ean.w = ea.w * 0.1f + su.w * 0.9f; en.w = ean.w / cc;
        reinterpret_cast<float4*>(out_eavg)[f4]  = ean;
        reinterpret_cast<float4*>(out_enorm)[f4] = en;
    }
}

// ---- quantize gather (runs last; out_q region doubles as scratch before) ----
__global__ __launch_bounds__(256) void vq_quant(
    const float* __restrict__ out_ind, const float* __restrict__ embed,
    float* __restrict__ out_q)
{
    __shared__ int inds[256];
    const int t = threadIdx.x;
    const int row0 = blockIdx.x * 256;
    inds[t] = (int)out_ind[row0 + t];
    __syncthreads();
    #pragma unroll
    for (int i = 0; i < 16; ++i) {
        const int f = t + i * 256;
        const int r = f >> 4, dq = f & 15;
        const int code = inds[r];
        const float4 ev = *reinterpret_cast<const float4*>(
            embed + (size_t)code * DDIM + dq * 4);
        *reinterpret_cast<float4*>(out_q + (size_t)(row0 + r) * DDIM + dq * 4) = ev;
    }
}

extern "C" void kernel_launch(void* const* d_in, const int* in_sizes, int n_in,
                              void* d_out, int out_size, void* d_ws, size_t ws_size,
                              hipStream_t stream)
{
    const float* x            = (const float*)d_in[0];
    const float* embed        = (const float*)d_in[1];
    const float* cluster_size = (const float*)d_in[2];
    const float* embed_avg    = (const float*)d_in[3];

    float* out      = (float*)d_out;
    float* out_q    = out;                                   // N*D (scratch until vq_quant)
    float* out_ind  = out_q + (size_t)NROWS * DDIM;          // N
    float* out_cs   = out_ind + NROWS;                       // K
    float* out_eavg = out_cs + KCODES;                       // K*D (embed_sum, then EMA)
    float* out_en   = out_eavg + (size_t)KCODES * DDIM;      // K*D (eb/e2f scratch, then enorm)

    unsigned short* eb = (unsigned short*)out_en;            // K*D bf16 = 128 KB
    float* e2f    = out_en + 32768;                          // K floats
    float* enmax2 = out_en + 32768 + KCODES;                 // 1 float

    int* S      = (int*)out_q;                               // scratch inside out_q
    int* candg  = S;                                         // N*8
    int* cntg   = S + 2097152;                               // N
    int* wl     = S + 2359296;                               // N
    int* sorted = S + 2621440;                               // N
    int* bins_i = S + 2883584;                               // K
    int* offs   = S + 2884608;                               // K
    int* cursor = S + 2885632;                               // K
    int* gcount = S + 2886656;                               // 1

    hipMemsetAsync(bins_i, 0, (3 * KCODES + 1) * sizeof(int), stream);
    hipMemsetAsync(enmax2, 0, sizeof(float), stream);

    vq_prep    <<<KCODES / 256, 256, 0, stream>>>(embed, eb, e2f, enmax2);
    vq_phaseA  <<<NROWS / 256, 512, 0, stream>>>(x, eb, e2f, enmax2,
                                                 out_ind, candg, cntg, wl, gcount);
    vq_rerank  <<<1024, 256, 0, stream>>>(x, embed, e2f, wl, gcount, cntg, candg, out_ind);
    vq_hist    <<<NROWS / 256, 256, 0, stream>>>(out_ind, bins_i);
    vq_prefix  <<<1, 1024, 0, stream>>>(bins_i, offs, cursor);
    vq_scatter <<<NROWS / 256, 256, 0, stream>>>(out_ind, cursor, sorted);
    vq_reduce  <<<KCODES, 256, 0, stream>>>(x, sorted, offs, bins_i, out_eavg);
    vq_finalize<<<1, 1024, 0, stream>>>(cluster_size, embed_avg, bins_i,
                                        out_cs, out_eavg, out_en);
    vq_quant   <<<NROWS / 256, 256, 0, stream>>>(out_ind, embed, out_q);
}

// Round 5
// 428.460 us; speedup vs baseline: 1.6213x; 1.2514x over previous
//
#include <hip/hip_runtime.h>
#include <hip/hip_bf16.h>

// VQ EuclideanCodebook round 5: MFMA candidate filter (tight 2^-6 margin) +
// thread-per-row exact f32 re-rank + atomic-free count-sort embed_sum/bins.

#define NROWS 262144
#define KCODES 1024
#define DDIM 64
#define CAPL 8

typedef __attribute__((ext_vector_type(8)))  short short8;
typedef __attribute__((ext_vector_type(16))) float f32x16;

__device__ __forceinline__ unsigned short f2bf(float f) {
    unsigned u = __float_as_uint(f);
    unsigned r = u + 0x7fffu + ((u >> 16) & 1u);   // RNE to bf16
    return (unsigned short)(r >> 16);
}

// ---- prep: e2 (exact f32, ascending fmaf), E->bf16, max ||e||^2 ----
__global__ __launch_bounds__(256) void vq_prep(
    const float* __restrict__ embed, unsigned short* __restrict__ eb,
    float* __restrict__ e2f, float* __restrict__ enmax2)
{
    const int k = blockIdx.x * 256 + threadIdx.x;   // 0..1023
    const float* er = embed + (size_t)k * DDIM;
    float s = 0.f;
    #pragma unroll
    for (int d = 0; d < DDIM; ++d) { float v = er[d]; s = fmaf(v, v, s); }
    e2f[k] = s;
    #pragma unroll
    for (int d = 0; d < DDIM; ++d) eb[(size_t)k * DDIM + d] = f2bf(er[d]);
    atomicMax((int*)enmax2, __float_as_int(s));     // s >= 0: int-monotone
}

// ---- phase A: MFMA approx sweeps, candidate collection, single-cand finalize ----
__global__ __launch_bounds__(512, 4) void vq_phaseA(
    const float* __restrict__ x, const unsigned short* __restrict__ eb,
    const float* __restrict__ e2f, const float* __restrict__ enmax2,
    float* __restrict__ out_ind, int* __restrict__ candg, int* __restrict__ cntg,
    int* __restrict__ wl, int* __restrict__ gcount,
    int* __restrict__ wl2, int* __restrict__ gcount2)
{
    __shared__ __align__(16) unsigned short ebs[8 * 32 * 64];  // 32 KB, swizzled
    __shared__ float norm2L[256];
    __shared__ int   cntL[256];
    __shared__ int   candL[256][CAPL];
    __shared__ int   mcount, mbase, mcount2, mbase2;

    const int t    = threadIdx.x;
    const int lane = t & 63;
    const int wid  = t >> 6;
    const int lo   = lane & 31;
    const int hi   = lane >> 5;
    const int rowb = blockIdx.x * 256;
    const int myrow = rowb + wid * 32 + lo;

    // A fragments (row=lane&31, k=16i+8hi+j) + row norms
    short8 af[4];
    float xsq = 0.f;
    {
        const float* xr = x + (size_t)myrow * DDIM;
        #pragma unroll
        for (int i = 0; i < 4; ++i) {
            const float4 a = *reinterpret_cast<const float4*>(xr + 16 * i + 8 * hi);
            const float4 b = *reinterpret_cast<const float4*>(xr + 16 * i + 8 * hi + 4);
            short8 f;
            f[0] = (short)f2bf(a.x); f[1] = (short)f2bf(a.y);
            f[2] = (short)f2bf(a.z); f[3] = (short)f2bf(a.w);
            f[4] = (short)f2bf(b.x); f[5] = (short)f2bf(b.y);
            f[6] = (short)f2bf(b.z); f[7] = (short)f2bf(b.w);
            af[i] = f;
            xsq = fmaf(a.x, a.x, xsq); xsq = fmaf(a.y, a.y, xsq);
            xsq = fmaf(a.z, a.z, xsq); xsq = fmaf(a.w, a.w, xsq);
            xsq = fmaf(b.x, b.x, xsq); xsq = fmaf(b.y, b.y, xsq);
            xsq = fmaf(b.z, b.z, xsq); xsq = fmaf(b.w, b.w, xsq);
        }
    }
    const float n2full = xsq + __shfl_xor(xsq, 32);
    if (hi == 0) norm2L[wid * 32 + lo] = n2full;
    if (t < 256) cntL[t] = 0;
    if (t == 0) { mcount = 0; mcount2 = 0; }
    const float en2 = *enmax2;

    f32x16 best;
    #pragma unroll
    for (int r = 0; r < 16; ++r) best[r] = 3.4e38f;

    // ---------- sweep 1 ----------
    for (int p = 0; p < 4; ++p) {
        __syncthreads();
        #pragma unroll
        for (int it = 0; it < 4; ++it) {       // stage 16 KB of eb, swizzled
            const int f16  = t + it * 512;     // 0..2047 16B segments
            const int ch8  = f16 >> 8;
            const int r    = f16 & 255;
            const int code = r >> 3, slot = r & 7;
            const short8 v = *reinterpret_cast<const short8*>(eb + (size_t)p * 16384 + f16 * 8);
            *reinterpret_cast<short8*>((char*)ebs + ch8 * 4096 + code * 128 +
                                       ((slot ^ (code & 7)) << 4)) = v;
        }
        __syncthreads();
        for (int c8 = 0; c8 < 8; ++c8) {
            const int ch = p * 8 + c8;
            short8 bfr[4];
            #pragma unroll
            for (int i = 0; i < 4; ++i) {
                const int slot = 2 * i + hi;
                bfr[i] = *reinterpret_cast<const short8*>(
                    (char*)ebs + c8 * 4096 + lo * 128 + (((slot ^ (lo & 7))) << 4));
            }
            const float e2l = e2f[ch * 32 + lo];
            f32x16 acc;
            #pragma unroll
            for (int r = 0; r < 16; ++r) acc[r] = 0.f;
            #pragma unroll
            for (int i = 0; i < 4; ++i)
                acc = __builtin_amdgcn_mfma_f32_32x32x16_bf16(af[i], bfr[i], acc, 0, 0, 0);
            #pragma unroll
            for (int r = 0; r < 16; ++r)
                best[r] = fminf(best[r], fmaf(-2.f, acc[r], e2l));
        }
    }

    // per-row min reduce + rigorous margin 2^-6*||x||*||e||max -> threshold
    #pragma unroll
    for (int r = 0; r < 16; ++r) {
        float v = best[r];
        v = fminf(v, __shfl_xor(v, 1));  v = fminf(v, __shfl_xor(v, 2));
        v = fminf(v, __shfl_xor(v, 4));  v = fminf(v, __shfl_xor(v, 8));
        v = fminf(v, __shfl_xor(v, 16));
        const int rr = (r & 3) + 8 * (r >> 2) + 4 * hi;
        const float nr2 = norm2L[wid * 32 + rr];
        best[r] = v + 0.015625f * sqrtf(nr2 * en2) + 1e-4f;
    }

    // ---------- sweep 2: recompute, collect candidates ----------
    for (int p = 0; p < 4; ++p) {
        __syncthreads();
        #pragma unroll
        for (int it = 0; it < 4; ++it) {
            const int f16  = t + it * 512;
            const int ch8  = f16 >> 8;
            const int r    = f16 & 255;
            const int code = r >> 3, slot = r & 7;
            const short8 v = *reinterpret_cast<const short8*>(eb + (size_t)p * 16384 + f16 * 8);
            *reinterpret_cast<short8*>((char*)ebs + ch8 * 4096 + code * 128 +
                                       ((slot ^ (code & 7)) << 4)) = v;
        }
        __syncthreads();
        for (int c8 = 0; c8 < 8; ++c8) {
            const int ch = p * 8 + c8;
            short8 bfr[4];
            #pragma unroll
            for (int i = 0; i < 4; ++i) {
                const int slot = 2 * i + hi;
                bfr[i] = *reinterpret_cast<const short8*>(
                    (char*)ebs + c8 * 4096 + lo * 128 + (((slot ^ (lo & 7))) << 4));
            }
            const float e2l = e2f[ch * 32 + lo];
            f32x16 acc;
            #pragma unroll
            for (int r = 0; r < 16; ++r) acc[r] = 0.f;
            #pragma unroll
            for (int i = 0; i < 4; ++i)
                acc = __builtin_amdgcn_mfma_f32_32x32x16_bf16(af[i], bfr[i], acc, 0, 0, 0);
            #pragma unroll
            for (int r = 0; r < 16; ++r) {
                const float d0 = fmaf(-2.f, acc[r], e2l);
                if (d0 <= best[r]) {
                    const int rr = (r & 3) + 8 * (r >> 2) + 4 * hi;
                    const int rl = wid * 32 + rr;
                    const int idx = atomicAdd(&cntL[rl], 1);
                    if (idx < CAPL) candL[rl][idx] = ch * 32 + lo;
                }
            }
        }
    }
    __syncthreads();

    // finalize single-candidate rows; enqueue multi (2..8) and overflow rows
    int my = -1, my2 = -1, c = 0;
    if (t < 256) {
        c = cntL[t];
        if (c == 1)           out_ind[rowb + t] = (float)candL[t][0];
        else if (c <= CAPL)   my  = atomicAdd(&mcount, 1);
        else                  my2 = atomicAdd(&mcount2, 1);
    }
    __syncthreads();
    if (t == 0) { mbase = atomicAdd(gcount, mcount); mbase2 = atomicAdd(gcount2, mcount2); }
    __syncthreads();
    if (my >= 0) {
        const int row = rowb + t;
        wl[mbase + my] = row;
        cntg[row] = c;
        #pragma unroll
        for (int j = 0; j < CAPL; ++j)
            if (j < c) candg[row * 8 + j] = candL[t][j];
    }
    if (my2 >= 0) wl2[mbase2 + my2] = rowb + t;
}

// ---- re-rank 2..8-candidate rows: one THREAD per row ----
__global__ __launch_bounds__(256) void vq_rerank1(
    const float* __restrict__ x, const float* __restrict__ embed,
    const float* __restrict__ e2f, const int* __restrict__ wl,
    const int* __restrict__ gcount, const int* __restrict__ cntg,
    const int* __restrict__ candg, float* __restrict__ out_ind)
{
    const int n = *gcount;
    for (int i = blockIdx.x * 256 + threadIdx.x; i < n; i += gridDim.x * 256) {
        const int row = wl[i];
        float xv[DDIM];
        {
            const float4* xp = reinterpret_cast<const float4*>(x + (size_t)row * DDIM);
            float4 xq[16];
            #pragma unroll
            for (int q = 0; q < 16; ++q) xq[q] = xp[q];      // independent loads (ILP)
            #pragma unroll
            for (int q = 0; q < 16; ++q) {
                xv[q*4+0] = xq[q].x; xv[q*4+1] = xq[q].y;
                xv[q*4+2] = xq[q].z; xv[q*4+3] = xq[q].w;
            }
        }
        float x2 = 0.f;
        #pragma unroll
        for (int d = 0; d < DDIM; ++d) x2 = fmaf(xv[d], xv[d], x2);

        const int c = cntg[row];
        float bv = 3.4e38f; int bk = 0x7fffffff;
        for (int ci = 0; ci < c; ++ci) {
            const int k = candg[row * 8 + ci];
            const float4* ep = reinterpret_cast<const float4*>(embed + (size_t)k * DDIM);
            float dot = 0.f;
            #pragma unroll
            for (int q = 0; q < 16; ++q) {
                const float4 e4 = ep[q];
                dot = fmaf(xv[q*4+0], e4.x, dot);
                dot = fmaf(xv[q*4+1], e4.y, dot);
                dot = fmaf(xv[q*4+2], e4.z, dot);
                dot = fmaf(xv[q*4+3], e4.w, dot);
            }
            const float dist = (x2 - 2.0f * dot) + e2f[k];
            if (dist < bv || (dist == bv && k < bk)) { bv = dist; bk = k; }
        }
        out_ind[row] = (float)bk;
    }
}

// ---- overflow rows: one WAVE per row, exact full scan ----
__global__ __launch_bounds__(256) void vq_rerank2(
    const float* __restrict__ x, const float* __restrict__ embed,
    const float* __restrict__ e2f, const int* __restrict__ wl2,
    const int* __restrict__ gcount2, float* __restrict__ out_ind)
{
    const int t    = threadIdx.x;
    const int lane = t & 63;
    const int gw   = (blockIdx.x * 256 + t) >> 6;
    const int nw   = (gridDim.x * 256) >> 6;
    const int n    = *gcount2;

    for (int e = gw; e < n; e += nw) {
        const int row = wl2[e];
        float xv[DDIM];
        {
            const float4* xp = reinterpret_cast<const float4*>(x + (size_t)row * DDIM);
            #pragma unroll
            for (int q = 0; q < 16; ++q) {
                const float4 v = xp[q];
                xv[q*4+0] = v.x; xv[q*4+1] = v.y; xv[q*4+2] = v.z; xv[q*4+3] = v.w;
            }
        }
        float x2 = 0.f;
        #pragma unroll
        for (int d = 0; d < DDIM; ++d) x2 = fmaf(xv[d], xv[d], x2);

        float bv = 3.4e38f; int bk = 0x7fffffff;
        for (int k = lane; k < KCODES; k += 64) {
            const float* er = embed + (size_t)k * DDIM;
            float dot = 0.f;
            #pragma unroll
            for (int d = 0; d < DDIM; ++d) dot = fmaf(xv[d], er[d], dot);
            const float dist = (x2 - 2.0f * dot) + e2f[k];
            if (dist < bv) { bv = dist; bk = k; }
        }
        #pragma unroll
        for (int s = 1; s < 64; s <<= 1) {
            const float ov = __shfl_xor(bv, s);
            const int   ok = __shfl_xor(bk, s);
            if (ov < bv || (ov == bv && ok < bk)) { bv = ov; bk = ok; }
        }
        if (lane == 0) out_ind[row] = (float)bk;
    }
}

// ---- histogram (int, LDS-aggregated) ----
__global__ __launch_bounds__(256) void vq_hist(
    const float* __restrict__ out_ind, int* __restrict__ bins_i)
{
    __shared__ int h[KCODES];
    const int t = threadIdx.x;
    #pragma unroll
    for (int j = 0; j < 4; ++j) h[t + 256 * j] = 0;
    __syncthreads();
    const int row = blockIdx.x * 256 + t;
    atomicAdd(&h[(int)out_ind[row]], 1);
    __syncthreads();
    #pragma unroll
    for (int j = 0; j < 4; ++j) {
        const int v = h[t + 256 * j];
        if (v) atomicAdd(bins_i + t + 256 * j, v);
    }
}

// ---- exclusive prefix over bins -> offs, cursor ----
__global__ __launch_bounds__(1024) void vq_prefix(
    const int* __restrict__ bins_i, int* __restrict__ offs, int* __restrict__ cursor)
{
    __shared__ int s[KCODES];
    const int t = threadIdx.x;
    const int b = bins_i[t];
    s[t] = b;
    __syncthreads();
    for (int d = 1; d < KCODES; d <<= 1) {
        const int v = (t >= d) ? s[t - d] : 0;
        __syncthreads();
        s[t] += v;
        __syncthreads();
    }
    const int excl = s[t] - b;
    offs[t] = excl;
    cursor[t] = excl;
}

// ---- scatter row ids into code-sorted order ----
__global__ __launch_bounds__(256) void vq_scatter(
    const float* __restrict__ out_ind, int* __restrict__ cursor, int* __restrict__ sorted)
{
    const int row  = blockIdx.x * 256 + threadIdx.x;
    const int code = (int)out_ind[row];
    const int pos  = atomicAdd(cursor + code, 1);
    sorted[pos] = row;
}

// ---- per-code gather-reduce: embed_sum (no atomics) ----
__global__ __launch_bounds__(256) void vq_reduce(
    const float* __restrict__ x, const int* __restrict__ sorted,
    const int* __restrict__ offs, const int* __restrict__ bins_i,
    float* __restrict__ esum)
{
    __shared__ float part[4][DDIM];
    const int t = threadIdx.x, lane = t & 63, w = t >> 6;
    const int k = blockIdx.x;
    const int off = offs[k], n = bins_i[k];
    float a0 = 0.f, a1 = 0.f;
    for (int i = w; i < n; i += 8) {
        const int r0 = sorted[off + i];
        const float v0 = x[(size_t)r0 * DDIM + lane];
        float v1 = 0.f;
        if (i + 4 < n) { const int r1 = sorted[off + i + 4]; v1 = x[(size_t)r1 * DDIM + lane]; }
        a0 += v0; a1 += v1;
    }
    part[w][lane] = a0 + a1;
    __syncthreads();
    if (t < DDIM)
        esum[(size_t)k * DDIM + t] = ((part[0][t] + part[1][t]) + part[2][t]) + part[3][t];
}

// ---- finalize: EMA + Laplace smoothing ----
__global__ __launch_bounds__(1024) void vq_finalize(
    const float* __restrict__ cluster_size, const float* __restrict__ embed_avg,
    const int* __restrict__ bins_i, float* __restrict__ out_cs,
    float* __restrict__ out_eavg, float* __restrict__ out_enorm)
{
    __shared__ float red[KCODES];
    __shared__ float css[KCODES];
    const int t = threadIdx.x;

    const float csn = cluster_size[t] * 0.1f + (float)bins_i[t] * 0.9f;
    red[t] = csn;
    __syncthreads();
    for (int s = 512; s > 0; s >>= 1) {
        if (t < s) red[t] += red[t + s];
        __syncthreads();
    }
    const float n = red[0];
    out_cs[t] = csn;
    css[t] = (csn + 1e-5f) / (n + (float)(KCODES * 1e-5)) * n;
    __syncthreads();

    #pragma unroll
    for (int i = 0; i < 16; ++i) {
        const int f4 = t + i * 1024;
        const int k  = f4 >> 4;
        const float4 ea = reinterpret_cast<const float4*>(embed_avg)[f4];
        const float4 su = reinterpret_cast<const float4*>(out_eavg)[f4];
        const float  cc = css[k];
        float4 ean, en;
        ean.x = ea.x * 0.1f + su.x * 0.9f; en.x = ean.x / cc;
        ean.y = ea.y * 0.1f + su.y * 0.9f; en.y = ean.y / cc;
        ean.z = ea.z * 0.1f + su.z * 0.9f; en.z = ean.z / cc;
        ean.w = ea.w * 0.1f + su.w * 0.9f; en.w = ean.w / cc;
        reinterpret_cast<float4*>(out_eavg)[f4]  = ean;
        reinterpret_cast<float4*>(out_enorm)[f4] = en;
    }
}

// ---- quantize gather (runs last; out_q region doubles as scratch before) ----
__global__ __launch_bounds__(256) void vq_quant(
    const float* __restrict__ out_ind, const float* __restrict__ embed,
    float* __restrict__ out_q)
{
    __shared__ int inds[256];
    const int t = threadIdx.x;
    const int row0 = blockIdx.x * 256;
    inds[t] = (int)out_ind[row0 + t];
    __syncthreads();
    #pragma unroll
    for (int i = 0; i < 16; ++i) {
        const int f = t + i * 256;
        const int r = f >> 4, dq = f & 15;
        const int code = inds[r];
        const float4 ev = *reinterpret_cast<const float4*>(
            embed + (size_t)code * DDIM + dq * 4);
        *reinterpret_cast<float4*>(out_q + (size_t)(row0 + r) * DDIM + dq * 4) = ev;
    }
}

extern "C" void kernel_launch(void* const* d_in, const int* in_sizes, int n_in,
                              void* d_out, int out_size, void* d_ws, size_t ws_size,
                              hipStream_t stream)
{
    const float* x            = (const float*)d_in[0];
    const float* embed        = (const float*)d_in[1];
    const float* cluster_size = (const float*)d_in[2];
    const float* embed_avg    = (const float*)d_in[3];

    float* out      = (float*)d_out;
    float* out_q    = out;                                   // N*D (scratch until vq_quant)
    float* out_ind  = out_q + (size_t)NROWS * DDIM;          // N
    float* out_cs   = out_ind + NROWS;                       // K
    float* out_eavg = out_cs + KCODES;                       // K*D (embed_sum, then EMA)
    float* out_en   = out_eavg + (size_t)KCODES * DDIM;      // K*D (eb/e2f scratch, then enorm)

    unsigned short* eb = (unsigned short*)out_en;            // K*D bf16 = 128 KB
    float* e2f    = out_en + 32768;                          // K floats
    float* enmax2 = out_en + 32768 + KCODES;                 // 1 float

    int* S      = (int*)out_q;                               // scratch inside out_q
    int* candg  = S;                                         // N*8
    int* cntg   = S + 2097152;                               // N
    int* wl     = S + 2359296;                               // N
    int* wl2    = S + 2621440;                               // N
    int* sorted = S + 2883584;                               // N
    int* bins_i = S + 3145728;                               // K
    int* offs   = bins_i + KCODES;                           // K
    int* cursor = offs + KCODES;                             // K
    int* gcount = cursor + KCODES;                           // 1
    int* gcount2= gcount + 1;                                // 1

    hipMemsetAsync(bins_i, 0, (3 * KCODES + 2) * sizeof(int), stream);
    hipMemsetAsync(enmax2, 0, sizeof(float), stream);

    vq_prep    <<<KCODES / 256, 256, 0, stream>>>(embed, eb, e2f, enmax2);
    vq_phaseA  <<<NROWS / 256, 512, 0, stream>>>(x, eb, e2f, enmax2, out_ind,
                                                 candg, cntg, wl, gcount, wl2, gcount2);
    vq_rerank1 <<<1024, 256, 0, stream>>>(x, embed, e2f, wl, gcount, cntg, candg, out_ind);
    vq_rerank2 <<<128, 256, 0, stream>>>(x, embed, e2f, wl2, gcount2, out_ind);
    vq_hist    <<<NROWS / 256, 256, 0, stream>>>(out_ind, bins_i);
    vq_prefix  <<<1, 1024, 0, stream>>>(bins_i, offs, cursor);
    vq_scatter <<<NROWS / 256, 256, 0, stream>>>(out_ind, cursor, sorted);
    vq_reduce  <<<KCODES, 256, 0, stream>>>(x, sorted, offs, bins_i, out_eavg);
    vq_finalize<<<1, 1024, 0, stream>>>(cluster_size, embed_avg, bins_i,
                                        out_cs, out_eavg, out_en);
    vq_quant   <<<NROWS / 256, 256, 0, stream>>>(out_ind, embed, out_q);
}

// Round 6
// 295.206 us; speedup vs baseline: 2.3531x; 1.4514x over previous
//
#include <hip/hip_runtime.h>
#include <hip/hip_bf16.h>

// VQ EuclideanCodebook round 6: MFMA candidate filter + thread-per-row exact
// re-rank + count-sort epilogue with BALANCED segmented reduce (packed
// code|row entries, position-partitioned, boundary-only atomics).

#define NROWS 262144
#define KCODES 1024
#define DDIM 64
#define CAPL 8

typedef __attribute__((ext_vector_type(8)))  short short8;
typedef __attribute__((ext_vector_type(16))) float f32x16;

__device__ __forceinline__ unsigned short f2bf(float f) {
    unsigned u = __float_as_uint(f);
    unsigned r = u + 0x7fffu + ((u >> 16) & 1u);   // RNE to bf16
    return (unsigned short)(r >> 16);
}

// ---- prep: e2 (exact f32, ascending fmaf), E->bf16, max ||e||^2 ----
__global__ __launch_bounds__(256) void vq_prep(
    const float* __restrict__ embed, unsigned short* __restrict__ eb,
    float* __restrict__ e2f, float* __restrict__ enmax2)
{
    const int k = blockIdx.x * 256 + threadIdx.x;   // 0..1023
    const float* er = embed + (size_t)k * DDIM;
    float s = 0.f;
    #pragma unroll
    for (int d = 0; d < DDIM; ++d) { float v = er[d]; s = fmaf(v, v, s); }
    e2f[k] = s;
    #pragma unroll
    for (int d = 0; d < DDIM; ++d) eb[(size_t)k * DDIM + d] = f2bf(er[d]);
    atomicMax((int*)enmax2, __float_as_int(s));     // s >= 0: int-monotone
}

// ---- phase A: MFMA approx sweeps, candidate collection, single-cand finalize ----
__global__ __launch_bounds__(512, 4) void vq_phaseA(
    const float* __restrict__ x, const unsigned short* __restrict__ eb,
    const float* __restrict__ e2f, const float* __restrict__ enmax2,
    float* __restrict__ out_ind, int* __restrict__ candg, int* __restrict__ cntg,
    int* __restrict__ wl, int* __restrict__ gcount,
    int* __restrict__ wl2, int* __restrict__ gcount2)
{
    __shared__ __align__(16) unsigned short ebs[8 * 32 * 64];  // 32 KB, swizzled
    __shared__ float norm2L[256];
    __shared__ int   cntL[256];
    __shared__ int   candL[256][CAPL];
    __shared__ int   mcount, mbase, mcount2, mbase2;

    const int t    = threadIdx.x;
    const int lane = t & 63;
    const int wid  = t >> 6;
    const int lo   = lane & 31;
    const int hi   = lane >> 5;
    const int rowb = blockIdx.x * 256;
    const int myrow = rowb + wid * 32 + lo;

    // A fragments (row=lane&31, k=16i+8hi+j) + row norms
    short8 af[4];
    float xsq = 0.f;
    {
        const float* xr = x + (size_t)myrow * DDIM;
        #pragma unroll
        for (int i = 0; i < 4; ++i) {
            const float4 a = *reinterpret_cast<const float4*>(xr + 16 * i + 8 * hi);
            const float4 b = *reinterpret_cast<const float4*>(xr + 16 * i + 8 * hi + 4);
            short8 f;
            f[0] = (short)f2bf(a.x); f[1] = (short)f2bf(a.y);
            f[2] = (short)f2bf(a.z); f[3] = (short)f2bf(a.w);
            f[4] = (short)f2bf(b.x); f[5] = (short)f2bf(b.y);
            f[6] = (short)f2bf(b.z); f[7] = (short)f2bf(b.w);
            af[i] = f;
            xsq = fmaf(a.x, a.x, xsq); xsq = fmaf(a.y, a.y, xsq);
            xsq = fmaf(a.z, a.z, xsq); xsq = fmaf(a.w, a.w, xsq);
            xsq = fmaf(b.x, b.x, xsq); xsq = fmaf(b.y, b.y, xsq);
            xsq = fmaf(b.z, b.z, xsq); xsq = fmaf(b.w, b.w, xsq);
        }
    }
    const float n2full = xsq + __shfl_xor(xsq, 32);
    if (hi == 0) norm2L[wid * 32 + lo] = n2full;
    if (t < 256) cntL[t] = 0;
    if (t == 0) { mcount = 0; mcount2 = 0; }
    const float en2 = *enmax2;

    f32x16 best;
    #pragma unroll
    for (int r = 0; r < 16; ++r) best[r] = 3.4e38f;

    // ---------- sweep 1 ----------
    for (int p = 0; p < 4; ++p) {
        __syncthreads();
        #pragma unroll
        for (int it = 0; it < 4; ++it) {       // stage 16 KB of eb, swizzled
            const int f16  = t + it * 512;     // 0..2047 16B segments
            const int ch8  = f16 >> 8;
            const int r    = f16 & 255;
            const int code = r >> 3, slot = r & 7;
            const short8 v = *reinterpret_cast<const short8*>(eb + (size_t)p * 16384 + f16 * 8);
            *reinterpret_cast<short8*>((char*)ebs + ch8 * 4096 + code * 128 +
                                       ((slot ^ (code & 7)) << 4)) = v;
        }
        __syncthreads();
        for (int c8 = 0; c8 < 8; ++c8) {
            const int ch = p * 8 + c8;
            short8 bfr[4];
            #pragma unroll
            for (int i = 0; i < 4; ++i) {
                const int slot = 2 * i + hi;
                bfr[i] = *reinterpret_cast<const short8*>(
                    (char*)ebs + c8 * 4096 + lo * 128 + (((slot ^ (lo & 7))) << 4));
            }
            const float e2l = e2f[ch * 32 + lo];
            f32x16 acc;
            #pragma unroll
            for (int r = 0; r < 16; ++r) acc[r] = 0.f;
            #pragma unroll
            for (int i = 0; i < 4; ++i)
                acc = __builtin_amdgcn_mfma_f32_32x32x16_bf16(af[i], bfr[i], acc, 0, 0, 0);
            #pragma unroll
            for (int r = 0; r < 16; ++r)
                best[r] = fminf(best[r], fmaf(-2.f, acc[r], e2l));
        }
    }

    // per-row min reduce + rigorous margin 2^-6*||x||*||e||max -> threshold
    #pragma unroll
    for (int r = 0; r < 16; ++r) {
        float v = best[r];
        v = fminf(v, __shfl_xor(v, 1));  v = fminf(v, __shfl_xor(v, 2));
        v = fminf(v, __shfl_xor(v, 4));  v = fminf(v, __shfl_xor(v, 8));
        v = fminf(v, __shfl_xor(v, 16));
        const int rr = (r & 3) + 8 * (r >> 2) + 4 * hi;
        const float nr2 = norm2L[wid * 32 + rr];
        best[r] = v + 0.015625f * sqrtf(nr2 * en2) + 1e-4f;
    }

    // ---------- sweep 2: recompute, collect candidates ----------
    for (int p = 0; p < 4; ++p) {
        __syncthreads();
        #pragma unroll
        for (int it = 0; it < 4; ++it) {
            const int f16  = t + it * 512;
            const int ch8  = f16 >> 8;
            const int r    = f16 & 255;
            const int code = r >> 3, slot = r & 7;
            const short8 v = *reinterpret_cast<const short8*>(eb + (size_t)p * 16384 + f16 * 8);
            *reinterpret_cast<short8*>((char*)ebs + ch8 * 4096 + code * 128 +
                                       ((slot ^ (code & 7)) << 4)) = v;
        }
        __syncthreads();
        for (int c8 = 0; c8 < 8; ++c8) {
            const int ch = p * 8 + c8;
            short8 bfr[4];
            #pragma unroll
            for (int i = 0; i < 4; ++i) {
                const int slot = 2 * i + hi;
                bfr[i] = *reinterpret_cast<const short8*>(
                    (char*)ebs + c8 * 4096 + lo * 128 + (((slot ^ (lo & 7))) << 4));
            }
            const float e2l = e2f[ch * 32 + lo];
            f32x16 acc;
            #pragma unroll
            for (int r = 0; r < 16; ++r) acc[r] = 0.f;
            #pragma unroll
            for (int i = 0; i < 4; ++i)
                acc = __builtin_amdgcn_mfma_f32_32x32x16_bf16(af[i], bfr[i], acc, 0, 0, 0);
            #pragma unroll
            for (int r = 0; r < 16; ++r) {
                const float d0 = fmaf(-2.f, acc[r], e2l);
                if (d0 <= best[r]) {
                    const int rr = (r & 3) + 8 * (r >> 2) + 4 * hi;
                    const int rl = wid * 32 + rr;
                    const int idx = atomicAdd(&cntL[rl], 1);
                    if (idx < CAPL) candL[rl][idx] = ch * 32 + lo;
                }
            }
        }
    }
    __syncthreads();

    // finalize single-candidate rows; enqueue multi (2..8) and overflow rows
    int my = -1, my2 = -1, c = 0;
    if (t < 256) {
        c = cntL[t];
        if (c == 1)           out_ind[rowb + t] = (float)candL[t][0];
        else if (c <= CAPL)   my  = atomicAdd(&mcount, 1);
        else                  my2 = atomicAdd(&mcount2, 1);
    }
    __syncthreads();
    if (t == 0) { mbase = atomicAdd(gcount, mcount); mbase2 = atomicAdd(gcount2, mcount2); }
    __syncthreads();
    if (my >= 0) {
        const int row = rowb + t;
        wl[mbase + my] = row;
        cntg[row] = c;
        #pragma unroll
        for (int j = 0; j < CAPL; ++j)
            if (j < c) candg[row * 8 + j] = candL[t][j];
    }
    if (my2 >= 0) wl2[mbase2 + my2] = rowb + t;
}

// ---- re-rank 2..8-candidate rows: one THREAD per row ----
__global__ __launch_bounds__(256) void vq_rerank1(
    const float* __restrict__ x, const float* __restrict__ embed,
    const float* __restrict__ e2f, const int* __restrict__ wl,
    const int* __restrict__ gcount, const int* __restrict__ cntg,
    const int* __restrict__ candg, float* __restrict__ out_ind)
{
    const int n = *gcount;
    for (int i = blockIdx.x * 256 + threadIdx.x; i < n; i += gridDim.x * 256) {
        const int row = wl[i];
        float xv[DDIM];
        {
            const float4* xp = reinterpret_cast<const float4*>(x + (size_t)row * DDIM);
            float4 xq[16];
            #pragma unroll
            for (int q = 0; q < 16; ++q) xq[q] = xp[q];      // independent loads (ILP)
            #pragma unroll
            for (int q = 0; q < 16; ++q) {
                xv[q*4+0] = xq[q].x; xv[q*4+1] = xq[q].y;
                xv[q*4+2] = xq[q].z; xv[q*4+3] = xq[q].w;
            }
        }
        float x2 = 0.f;
        #pragma unroll
        for (int d = 0; d < DDIM; ++d) x2 = fmaf(xv[d], xv[d], x2);

        const int c = cntg[row];
        float bv = 3.4e38f; int bk = 0x7fffffff;
        for (int ci = 0; ci < c; ++ci) {
            const int k = candg[row * 8 + ci];
            const float4* ep = reinterpret_cast<const float4*>(embed + (size_t)k * DDIM);
            float dot = 0.f;
            #pragma unroll
            for (int q = 0; q < 16; ++q) {
                const float4 e4 = ep[q];
                dot = fmaf(xv[q*4+0], e4.x, dot);
                dot = fmaf(xv[q*4+1], e4.y, dot);
                dot = fmaf(xv[q*4+2], e4.z, dot);
                dot = fmaf(xv[q*4+3], e4.w, dot);
            }
            const float dist = (x2 - 2.0f * dot) + e2f[k];
            if (dist < bv || (dist == bv && k < bk)) { bv = dist; bk = k; }
        }
        out_ind[row] = (float)bk;
    }
}

// ---- overflow rows: one WAVE per row, exact full scan ----
__global__ __launch_bounds__(256) void vq_rerank2(
    const float* __restrict__ x, const float* __restrict__ embed,
    const float* __restrict__ e2f, const int* __restrict__ wl2,
    const int* __restrict__ gcount2, float* __restrict__ out_ind)
{
    const int t    = threadIdx.x;
    const int lane = t & 63;
    const int gw   = (blockIdx.x * 256 + t) >> 6;
    const int nw   = (gridDim.x * 256) >> 6;
    const int n    = *gcount2;

    for (int e = gw; e < n; e += nw) {
        const int row = wl2[e];
        float xv[DDIM];
        {
            const float4* xp = reinterpret_cast<const float4*>(x + (size_t)row * DDIM);
            #pragma unroll
            for (int q = 0; q < 16; ++q) {
                const float4 v = xp[q];
                xv[q*4+0] = v.x; xv[q*4+1] = v.y; xv[q*4+2] = v.z; xv[q*4+3] = v.w;
            }
        }
        float x2 = 0.f;
        #pragma unroll
        for (int d = 0; d < DDIM; ++d) x2 = fmaf(xv[d], xv[d], x2);

        float bv = 3.4e38f; int bk = 0x7fffffff;
        for (int k = lane; k < KCODES; k += 64) {
            const float* er = embed + (size_t)k * DDIM;
            float dot = 0.f;
            #pragma unroll
            for (int d = 0; d < DDIM; ++d) dot = fmaf(xv[d], er[d], dot);
            const float dist = (x2 - 2.0f * dot) + e2f[k];
            if (dist < bv) { bv = dist; bk = k; }
        }
        #pragma unroll
        for (int s = 1; s < 64; s <<= 1) {
            const float ov = __shfl_xor(bv, s);
            const int   ok = __shfl_xor(bk, s);
            if (ov < bv || (ov == bv && ok < bk)) { bv = ov; bk = ok; }
        }
        if (lane == 0) out_ind[row] = (float)bk;
    }
}

// ---- histogram (int, LDS-aggregated) ----
__global__ __launch_bounds__(256) void vq_hist(
    const float* __restrict__ out_ind, int* __restrict__ bins_i)
{
    __shared__ int h[KCODES];
    const int t = threadIdx.x;
    #pragma unroll
    for (int j = 0; j < 4; ++j) h[t + 256 * j] = 0;
    __syncthreads();
    const int row = blockIdx.x * 256 + t;
    atomicAdd(&h[(int)out_ind[row]], 1);
    __syncthreads();
    #pragma unroll
    for (int j = 0; j < 4; ++j) {
        const int v = h[t + 256 * j];
        if (v) atomicAdd(bins_i + t + 256 * j, v);
    }
}

// ---- exclusive prefix over bins -> offs, cursor ----
__global__ __launch_bounds__(1024) void vq_prefix(
    const int* __restrict__ bins_i, int* __restrict__ offs, int* __restrict__ cursor)
{
    __shared__ int s[KCODES];
    const int t = threadIdx.x;
    const int b = bins_i[t];
    s[t] = b;
    __syncthreads();
    for (int d = 1; d < KCODES; d <<= 1) {
        const int v = (t >= d) ? s[t - d] : 0;
        __syncthreads();
        s[t] += v;
        __syncthreads();
    }
    const int excl = s[t] - b;
    offs[t] = excl;
    cursor[t] = excl;
}

// ---- scatter packed (code<<20)|row into code-sorted order ----
__global__ __launch_bounds__(256) void vq_scatter(
    const float* __restrict__ out_ind, int* __restrict__ cursor, int* __restrict__ sorted)
{
    const int row  = blockIdx.x * 256 + threadIdx.x;
    const int code = (int)out_ind[row];
    const int pos  = atomicAdd(cursor + code, 1);
    sorted[pos] = (code << 20) | row;
}

// ---- balanced segmented reduce: 64 positions per wave, boundary atomics ----
__global__ __launch_bounds__(256) void vq_reduce(
    const float* __restrict__ x, const int* __restrict__ sorted,
    float* __restrict__ esum)
{
    const int t = threadIdx.x, lane = t & 63, w = t >> 6;
    const int p0 = (blockIdx.x * 4 + w) * 64;     // this wave's 64 positions

    int cur = sorted[p0] >> 20;
    float acc = 0.f;
    #pragma unroll 4
    for (int i = 0; i < 64; i += 4) {
        const int4 e4 = *reinterpret_cast<const int4*>(sorted + p0 + i);
        // issue all 4 row loads up front (independent -> latency overlap)
        const float v0 = x[(size_t)(e4.x & 0xFFFFF) * DDIM + lane];
        const float v1 = x[(size_t)(e4.y & 0xFFFFF) * DDIM + lane];
        const float v2 = x[(size_t)(e4.z & 0xFFFFF) * DDIM + lane];
        const float v3 = x[(size_t)(e4.w & 0xFFFFF) * DDIM + lane];
        const int c0 = e4.x >> 20, c1 = e4.y >> 20, c2 = e4.z >> 20, c3 = e4.w >> 20;
        if (c0 != cur) { unsafeAtomicAdd(esum + cur * DDIM + lane, acc); acc = 0.f; cur = c0; }
        acc += v0;
        if (c1 != cur) { unsafeAtomicAdd(esum + cur * DDIM + lane, acc); acc = 0.f; cur = c1; }
        acc += v1;
        if (c2 != cur) { unsafeAtomicAdd(esum + cur * DDIM + lane, acc); acc = 0.f; cur = c2; }
        acc += v2;
        if (c3 != cur) { unsafeAtomicAdd(esum + cur * DDIM + lane, acc); acc = 0.f; cur = c3; }
        acc += v3;
    }
    unsafeAtomicAdd(esum + cur * DDIM + lane, acc);
}

// ---- finalize: EMA + Laplace smoothing ----
__global__ __launch_bounds__(1024) void vq_finalize(
    const float* __restrict__ cluster_size, const float* __restrict__ embed_avg,
    const int* __restrict__ bins_i, float* __restrict__ out_cs,
    float* __restrict__ out_eavg, float* __restrict__ out_enorm)
{
    __shared__ float red[KCODES];
    __shared__ float css[KCODES];
    const int t = threadIdx.x;

    const float csn = cluster_size[t] * 0.1f + (float)bins_i[t] * 0.9f;
    red[t] = csn;
    __syncthreads();
    for (int s = 512; s > 0; s >>= 1) {
        if (t < s) red[t] += red[t + s];
        __syncthreads();
    }
    const float n = red[0];
    out_cs[t] = csn;
    css[t] = (csn + 1e-5f) / (n + (float)(KCODES * 1e-5)) * n;
    __syncthreads();

    #pragma unroll
    for (int i = 0; i < 16; ++i) {
        const int f4 = t + i * 1024;
        const int k  = f4 >> 4;
        const float4 ea = reinterpret_cast<const float4*>(embed_avg)[f4];
        const float4 su = reinterpret_cast<const float4*>(out_eavg)[f4];
        const float  cc = css[k];
        float4 ean, en;
        ean.x = ea.x * 0.1f + su.x * 0.9f; en.x = ean.x / cc;
        ean.y = ea.y * 0.1f + su.y * 0.9f; en.y = ean.y / cc;
        ean.z = ea.z * 0.1f + su.z * 0.9f; en.z = ean.z / cc;
        ean.w = ea.w * 0.1f + su.w * 0.9f; en.w = ean.w / cc;
        reinterpret_cast<float4*>(out_eavg)[f4]  = ean;
        reinterpret_cast<float4*>(out_enorm)[f4] = en;
    }
}

// ---- quantize gather (runs last; out_q region doubles as scratch before) ----
__global__ __launch_bounds__(256) void vq_quant(
    const float* __restrict__ out_ind, const float* __restrict__ embed,
    float* __restrict__ out_q)
{
    __shared__ int inds[256];
    const int t = threadIdx.x;
    const int row0 = blockIdx.x * 256;
    inds[t] = (int)out_ind[row0 + t];
    __syncthreads();
    #pragma unroll
    for (int i = 0; i < 16; ++i) {
        const int f = t + i * 256;
        const int r = f >> 4, dq = f & 15;
        const int code = inds[r];
        const float4 ev = *reinterpret_cast<const float4*>(
            embed + (size_t)code * DDIM + dq * 4);
        *reinterpret_cast<float4*>(out_q + (size_t)(row0 + r) * DDIM + dq * 4) = ev;
    }
}

extern "C" void kernel_launch(void* const* d_in, const int* in_sizes, int n_in,
                              void* d_out, int out_size, void* d_ws, size_t ws_size,
                              hipStream_t stream)
{
    const float* x            = (const float*)d_in[0];
    const float* embed        = (const float*)d_in[1];
    const float* cluster_size = (const float*)d_in[2];
    const float* embed_avg    = (const float*)d_in[3];

    float* out      = (float*)d_out;
    float* out_q    = out;                                   // N*D (scratch until vq_quant)
    float* out_ind  = out_q + (size_t)NROWS * DDIM;          // N
    float* out_cs   = out_ind + NROWS;                       // K
    float* out_eavg = out_cs + KCODES;                       // K*D (embed_sum accum, then EMA)
    float* out_en   = out_eavg + (size_t)KCODES * DDIM;      // K*D (eb/e2f scratch, then enorm)

    unsigned short* eb = (unsigned short*)out_en;            // K*D bf16 = 128 KB
    float* e2f    = out_en + 32768;                          // K floats
    float* enmax2 = out_en + 32768 + KCODES;                 // 1 float

    int* S      = (int*)out_q;                               // scratch inside out_q
    int* candg  = S;                                         // N*8
    int* cntg   = S + 2097152;                               // N
    int* wl     = S + 2359296;                               // N
    int* wl2    = S + 2621440;                               // N
    int* sorted = S + 2883584;                               // N
    int* bins_i = S + 3145728;                               // K
    int* offs   = bins_i + KCODES;                           // K
    int* cursor = offs + KCODES;                             // K
    int* gcount = cursor + KCODES;                           // 1
    int* gcount2= gcount + 1;                                // 1

    hipMemsetAsync(bins_i, 0, (3 * KCODES + 2) * sizeof(int), stream);
    hipMemsetAsync(out_eavg, 0, (size_t)KCODES * DDIM * sizeof(float), stream);
    hipMemsetAsync(enmax2, 0, sizeof(float), stream);

    vq_prep    <<<KCODES / 256, 256, 0, stream>>>(embed, eb, e2f, enmax2);
    vq_phaseA  <<<NROWS / 256, 512, 0, stream>>>(x, eb, e2f, enmax2, out_ind,
                                                 candg, cntg, wl, gcount, wl2, gcount2);
    vq_rerank1 <<<1024, 256, 0, stream>>>(x, embed, e2f, wl, gcount, cntg, candg, out_ind);
    vq_rerank2 <<<128, 256, 0, stream>>>(x, embed, e2f, wl2, gcount2, out_ind);
    vq_hist    <<<NROWS / 256, 256, 0, stream>>>(out_ind, bins_i);
    vq_prefix  <<<1, 1024, 0, stream>>>(bins_i, offs, cursor);
    vq_scatter <<<NROWS / 256, 256, 0, stream>>>(out_ind, cursor, sorted);
    vq_reduce  <<<NROWS / 256, 256, 0, stream>>>(x, sorted, out_eavg);
    vq_finalize<<<1, 1024, 0, stream>>>(cluster_size, embed_avg, bins_i,
                                        out_cs, out_eavg, out_en);
    vq_quant   <<<NROWS / 256, 256, 0, stream>>>(out_ind, embed, out_q);
}